// Round 3
// baseline (2255.959 us; speedup 1.0000x reference)
//
#include <hip/hip_runtime.h>
#include <math.h>

// ---------------- kernels ----------------

__global__ void deg_kernel(const int* __restrict__ dst, int* __restrict__ cnt, int E) {
    int tid = blockIdx.x * blockDim.x + threadIdx.x;
    int stride = gridDim.x * blockDim.x;
    for (int e = tid; e < E; e += stride)
        atomicAdd(&cnt[dst[e]], 1);
}

__global__ void dinv_kernel(const int* __restrict__ cnt, float* __restrict__ dinv, int N) {
    int tid = blockIdx.x * blockDim.x + threadIdx.x;
    int stride = gridDim.x * blockDim.x;
    for (int v = tid; v < N; v += stride)
        dinv[v] = rsqrtf((float)(cnt[v] + 1));   // +1 self loop; always > 0
}

// out[N,C] = X[N,K] @ W[K,C].
// Block = 256 threads = 16-row tile. X tile staged in LDS via coalesced float4;
// W staged in LDS once. Thread (c = tid&63, r0 = tid>>6) computes rows
// {r0, r0+4, r0+8, r0+12} at col c. Ws reads: 2-way bank (free); Xs reads:
// wave-uniform broadcast (free).
template <int K, int C>
__launch_bounds__(256, 4)
__global__ void gemm_kernel(const float* __restrict__ X, const float* __restrict__ W,
                            float* __restrict__ out, int N) {
    constexpr int ROWS = 16;
    constexpr int KV = K / 4;             // float4s per row
    __shared__ float  Ws[K * C];
    __shared__ float4 Xs[ROWS * KV];

    // stage W (coalesced)
    const float4* W4 = (const float4*)W;
    float4* Ws4 = (float4*)Ws;
    for (int i = threadIdx.x; i < K * C / 4; i += blockDim.x) Ws4[i] = W4[i];

    int tile = blockIdx.x * ROWS;
    // stage X tile (coalesced float4: lane i -> flat element i)
    const float4* X4 = (const float4*)(X + (size_t)tile * K);
    bool full = (tile + ROWS <= N);
    for (int i = threadIdx.x; i < ROWS * KV; i += blockDim.x) {
        float4 v = make_float4(0.f, 0.f, 0.f, 0.f);
        if (full || (tile + i / KV) < N) v = X4[i];
        Xs[i] = v;
    }
    __syncthreads();

    int c  = threadIdx.x & 63;
    int r0 = threadIdx.x >> 6;            // 0..3
    if (c < C) {
        float acc0 = 0.f, acc1 = 0.f, acc2 = 0.f, acc3 = 0.f;
#pragma unroll
        for (int k4 = 0; k4 < KV; ++k4) {
            int k = 4 * k4;
            float w0 = Ws[(k + 0) * C + c];
            float w1 = Ws[(k + 1) * C + c];
            float w2 = Ws[(k + 2) * C + c];
            float w3 = Ws[(k + 3) * C + c];
            float4 xv;
            xv = Xs[(r0 +  0) * KV + k4];
            acc0 += xv.x * w0 + xv.y * w1 + xv.z * w2 + xv.w * w3;
            xv = Xs[(r0 +  4) * KV + k4];
            acc1 += xv.x * w0 + xv.y * w1 + xv.z * w2 + xv.w * w3;
            xv = Xs[(r0 +  8) * KV + k4];
            acc2 += xv.x * w0 + xv.y * w1 + xv.z * w2 + xv.w * w3;
            xv = Xs[(r0 + 12) * KV + k4];
            acc3 += xv.x * w0 + xv.y * w1 + xv.z * w2 + xv.w * w3;
        }
        int row = tile + r0;
        if (row      < N) out[(size_t)(row     ) * C + c] = acc0;
        if (row + 4  < N) out[(size_t)(row + 4 ) * C + c] = acc1;
        if (row + 8  < N) out[(size_t)(row + 8 ) * C + c] = acc2;
        if (row + 12 < N) out[(size_t)(row + 12) * C + c] = acc3;
    }
}

// out[dst,:] += feat[src,:] * dinv[src]*dinv[dst]; one wave per edge, lane = col.
template <int C>
__global__ void scatter_kernel(const float* __restrict__ feat, const int* __restrict__ src,
                               const int* __restrict__ dst, const float* __restrict__ dinv,
                               float* __restrict__ out, int E) {
    int gtid = blockIdx.x * blockDim.x + threadIdx.x;
    int wave = gtid >> 6;
    int lane = threadIdx.x & 63;
    int nw = (gridDim.x * blockDim.x) >> 6;
    for (int e = wave; e < E; e += nw) {
        int s = src[e];
        int d = dst[e];
        float norm = dinv[s] * dinv[d];
        if (lane < C)
            atomicAdd(&out[(size_t)d * C + lane], feat[(size_t)s * C + lane] * norm);
    }
}

// B = relu(B + A*dinv^2 (self loop) + bias), C=64
__global__ void bias_relu_kernel(float* __restrict__ B, const float* __restrict__ A,
                                 const float* __restrict__ dinv, const float* __restrict__ b, int N) {
    int tid = blockIdx.x * blockDim.x + threadIdx.x;
    int stride = gridDim.x * blockDim.x;
    int total = N * 64;
    for (int i = tid; i < total; i += stride) {
        int v = i >> 6;
        int j = i & 63;
        float di = dinv[v];
        float val = B[i] + A[i] * di * di + b[j];
        B[i] = val > 0.f ? val : 0.f;
    }
}

// out[v,:] = log_softmax(softmax(out[v,:] + A2[v,:]*dinv^2 + b)), row width 40, wave per row
__global__ void softmax_kernel(float* __restrict__ out, const float* __restrict__ A2,
                               const float* __restrict__ dinv, const float* __restrict__ b, int N) {
    int gtid = blockIdx.x * blockDim.x + threadIdx.x;
    int wave = gtid >> 6;
    int lane = threadIdx.x & 63;
    int nw = (gridDim.x * blockDim.x) >> 6;
    for (int v = wave; v < N; v += nw) {
        bool act = lane < 40;
        float di = dinv[v];
        size_t idx = (size_t)v * 40 + lane;
        float z = act ? (out[idx] + A2[idx] * di * di + b[lane]) : -INFINITY;
        // softmax
        float m = z;
        for (int off = 32; off; off >>= 1) m = fmaxf(m, __shfl_xor(m, off));
        float e = act ? expf(z - m) : 0.f;
        float s = e;
        for (int off = 32; off; off >>= 1) s += __shfl_xor(s, off);
        float p = e / s;
        // log_softmax of p
        float m2 = act ? p : -INFINITY;
        for (int off = 32; off; off >>= 1) m2 = fmaxf(m2, __shfl_xor(m2, off));
        float e2 = act ? expf(p - m2) : 0.f;
        float s2 = e2;
        for (int off = 32; off; off >>= 1) s2 += __shfl_xor(s2, off);
        if (act) out[idx] = (p - m2) - logf(s2);
    }
}

// ---------------- launch ----------------

extern "C" void kernel_launch(void* const* d_in, const int* in_sizes, int n_in,
                              void* d_out, int out_size, void* d_ws, size_t ws_size,
                              hipStream_t stream) {
    const float* x  = (const float*)d_in[0];
    const int*   ei = (const int*)d_in[1];     // harness converts integer inputs to int32
    const float* W1 = (const float*)d_in[2];
    const float* b1 = (const float*)d_in[3];
    const float* W2 = (const float*)d_in[4];
    const float* b2 = (const float*)d_in[5];
    float* out = (float*)d_out;

    int N = in_sizes[0] / 128;
    int E = in_sizes[1] / 2;
    const int* src = ei;
    const int* dst = ei + E;

    char* ws = (char*)d_ws;
    size_t o = 0;
    int*   cnt  = (int*)(ws + o);   o += (((size_t)N * 4) + 255) & ~(size_t)255;
    float* dinv = (float*)(ws + o); o += (((size_t)N * 4) + 255) & ~(size_t)255;
    float* A    = (float*)(ws + o); o += (((size_t)N * 64 * 4) + 255) & ~(size_t)255;
    float* B    = (float*)(ws + o); o += (((size_t)N * 64 * 4) + 255) & ~(size_t)255;

    int gemm_grid = (N + 15) / 16;

    // degree + norm
    hipMemsetAsync(cnt, 0, (size_t)N * 4, stream);
    deg_kernel<<<1024, 256, 0, stream>>>(dst, cnt, E);
    dinv_kernel<<<256, 256, 0, stream>>>(cnt, dinv, N);

    // layer 1: A = x@W1 ; B = scatter(A) ; B = relu(B + selfloop + b1)
    gemm_kernel<128, 64><<<gemm_grid, 256, 0, stream>>>(x, W1, A, N);
    hipMemsetAsync(B, 0, (size_t)N * 64 * 4, stream);
    scatter_kernel<64><<<4096, 256, 0, stream>>>(A, src, dst, dinv, B, E);
    bias_relu_kernel<<<2048, 256, 0, stream>>>(B, A, dinv, b1, N);

    // layer 2: A = B@W2 ; out = scatter(A) ; out = log_softmax(softmax(out + selfloop + b2))
    gemm_kernel<64, 40><<<gemm_grid, 256, 0, stream>>>(B, W2, A, N);
    hipMemsetAsync(out, 0, (size_t)N * 40 * 4, stream);
    scatter_kernel<40><<<4096, 256, 0, stream>>>(A, src, dst, dinv, out, E);
    softmax_kernel<<<2048, 256, 0, stream>>>(out, A, dinv, b2, N);
}

// Round 4
// 1848.628 us; speedup vs baseline: 1.2203x; 1.2203x over previous
//
#include <hip/hip_runtime.h>
#include <math.h>

// ---------------- CSR build ----------------

__global__ void deg_kernel(const int* __restrict__ dst, int* __restrict__ cnt, int E) {
    int tid = blockIdx.x * blockDim.x + threadIdx.x;
    int stride = gridDim.x * blockDim.x;
    for (int e = tid; e < E; e += stride) atomicAdd(&cnt[dst[e]], 1);
}

__global__ void dinv_kernel(const int* __restrict__ cnt, float* __restrict__ dinv, int N) {
    int tid = blockIdx.x * blockDim.x + threadIdx.x;
    int stride = gridDim.x * blockDim.x;
    for (int v = tid; v < N; v += stride) dinv[v] = rsqrtf((float)(cnt[v] + 1)); // +1 self loop
}

// exclusive scan of cnt, 1024 elements per 256-thread block
__global__ void scan1_kernel(const int* __restrict__ cnt, int* __restrict__ excl,
                             int* __restrict__ bsum, int N) {
    int t = threadIdx.x;
    int base = blockIdx.x * 1024 + t * 4;
    int a0 = base + 0 < N ? cnt[base + 0] : 0;
    int a1 = base + 1 < N ? cnt[base + 1] : 0;
    int a2 = base + 2 < N ? cnt[base + 2] : 0;
    int a3 = base + 3 < N ? cnt[base + 3] : 0;
    int s = a0 + a1 + a2 + a3;
    int lane = t & 63, w = t >> 6;
    int inc = s;
    for (int off = 1; off < 64; off <<= 1) {
        int v = __shfl_up(inc, off);
        if (lane >= off) inc += v;
    }
    __shared__ int wsum[4];
    if (lane == 63) wsum[w] = inc;
    __syncthreads();
    int woff = 0;
    for (int i = 0; i < w; ++i) woff += wsum[i];
    int ex = woff + inc - s;
    if (base + 0 < N) excl[base + 0] = ex;
    if (base + 1 < N) excl[base + 1] = ex + a0;
    if (base + 2 < N) excl[base + 2] = ex + a0 + a1;
    if (base + 3 < N) excl[base + 3] = ex + a0 + a1 + a2;
    if (t == 255) bsum[blockIdx.x] = woff + inc;
}

// scan of per-block sums (nb <= 256), one 256-thread block
__global__ void scan2_kernel(const int* __restrict__ bsum, int* __restrict__ bsum2, int nb) {
    int t = threadIdx.x;
    int s = t < nb ? bsum[t] : 0;
    int lane = t & 63, w = t >> 6;
    int inc = s;
    for (int off = 1; off < 64; off <<= 1) {
        int v = __shfl_up(inc, off);
        if (lane >= off) inc += v;
    }
    __shared__ int wsum[4];
    if (lane == 63) wsum[w] = inc;
    __syncthreads();
    int woff = 0;
    for (int i = 0; i < w; ++i) woff += wsum[i];
    if (t < nb) bsum2[t] = woff + inc - s;
}

__global__ void scan3_kernel(const int* __restrict__ excl, const int* __restrict__ bsum2,
                             int* __restrict__ rowptr, int* __restrict__ cursor, int N, int E) {
    int tid = blockIdx.x * blockDim.x + threadIdx.x;
    int stride = gridDim.x * blockDim.x;
    for (int i = tid; i < N; i += stride) {
        int r = excl[i] + bsum2[i >> 10];
        rowptr[i] = r;
        cursor[i] = r;
    }
    if (tid == 0) rowptr[N] = E;
}

__global__ void bucket_kernel(const int* __restrict__ src, const int* __restrict__ dst,
                              int* __restrict__ cursor, int* __restrict__ esrc, int E) {
    int tid = blockIdx.x * blockDim.x + threadIdx.x;
    int stride = gridDim.x * blockDim.x;
    for (int e = tid; e < E; e += stride) {
        int p = atomicAdd(&cursor[dst[e]], 1);
        esrc[p] = src[e];
    }
}

// ---------------- layer kernels ----------------

// Ap[N,64] = (X[N,128] @ W1) * dinv[row].  Persistent blocks: W staged once,
// grid-stride over 16-row tiles staged in LDS via coalesced float4.
template <int K, int C>
__launch_bounds__(256, 4)
__global__ void gemm1_kernel(const float* __restrict__ X, const float* __restrict__ W,
                             const float* __restrict__ dinv, float* __restrict__ out, int N) {
    constexpr int ROWS = 16;
    constexpr int KV = K / 4;
    __shared__ float  Ws[K * C];
    __shared__ float4 Xs[ROWS * KV];
    const float4* W4 = (const float4*)W;
    float4* Ws4 = (float4*)Ws;
    for (int i = threadIdx.x; i < K * C / 4; i += 256) Ws4[i] = W4[i];
    int ntiles = (N + ROWS - 1) / ROWS;
    int c = threadIdx.x & 63, r0 = threadIdx.x >> 6;
    for (int tile_i = blockIdx.x; tile_i < ntiles; tile_i += gridDim.x) {
        int tile = tile_i * ROWS;
        __syncthreads();                       // Ws ready (1st iter) / Xs WAR (later)
        const float4* X4 = (const float4*)(X + (size_t)tile * K);
        bool full = tile + ROWS <= N;
        for (int i = threadIdx.x; i < ROWS * KV; i += 256) {
            float4 v = make_float4(0.f, 0.f, 0.f, 0.f);
            if (full || tile + i / KV < N) v = X4[i];
            Xs[i] = v;
        }
        __syncthreads();
        if (c < C) {
            float acc0 = 0.f, acc1 = 0.f, acc2 = 0.f, acc3 = 0.f;
#pragma unroll
            for (int k4 = 0; k4 < KV; ++k4) {
                int k = 4 * k4;
                float w0 = Ws[(k + 0) * C + c];
                float w1 = Ws[(k + 1) * C + c];
                float w2 = Ws[(k + 2) * C + c];
                float w3 = Ws[(k + 3) * C + c];
                float4 xv;
                xv = Xs[(r0 +  0) * KV + k4];
                acc0 += xv.x * w0 + xv.y * w1 + xv.z * w2 + xv.w * w3;
                xv = Xs[(r0 +  4) * KV + k4];
                acc1 += xv.x * w0 + xv.y * w1 + xv.z * w2 + xv.w * w3;
                xv = Xs[(r0 +  8) * KV + k4];
                acc2 += xv.x * w0 + xv.y * w1 + xv.z * w2 + xv.w * w3;
                xv = Xs[(r0 + 12) * KV + k4];
                acc3 += xv.x * w0 + xv.y * w1 + xv.z * w2 + xv.w * w3;
            }
            int row = tile + r0;
            if (row      < N) out[(size_t)(row     ) * C + c] = acc0 * dinv[row];
            if (row + 4  < N) out[(size_t)(row + 4 ) * C + c] = acc1 * dinv[row + 4];
            if (row + 8  < N) out[(size_t)(row + 8 ) * C + c] = acc2 * dinv[row + 8];
            if (row + 12 < N) out[(size_t)(row + 12) * C + c] = acc3 * dinv[row + 12];
        }
    }
}

// Wave per node: gather Ap rows via CSR, h = relu(dinv*(sum + Ap[v]*dinv) + b1),
// then fused GEMM2 via __shfl broadcast against LDS W2: A2p[v,c] = (h @ W2)[c] * dinv.
__global__ void layer_mid_kernel(const float* __restrict__ Ap, const int* __restrict__ esrc,
                                 const int* __restrict__ rowptr, const float* __restrict__ dinv,
                                 const float* __restrict__ W2, const float* __restrict__ b1,
                                 float* __restrict__ A2p, int N) {
    __shared__ float Ws[64 * 40];
    for (int i = threadIdx.x; i < 64 * 40; i += 256) Ws[i] = W2[i];
    __syncthreads();
    int gtid = blockIdx.x * blockDim.x + threadIdx.x;
    int wave = gtid >> 6, lane = threadIdx.x & 63;
    int nw = (gridDim.x * blockDim.x) >> 6;
    for (int v = wave; v < N; v += nw) {
        int i0 = rowptr[v], i1 = rowptr[v + 1];
        float acc = 0.f;
        for (int base = i0; base < i1; base += 64) {
            int n = min(64, i1 - base);
            int el = (lane < n) ? esrc[base + lane] : 0;
            int j = 0;
            for (; j + 4 <= n; j += 4) {
                int s0 = __shfl(el, j), s1 = __shfl(el, j + 1);
                int s2 = __shfl(el, j + 2), s3 = __shfl(el, j + 3);
                float f0 = Ap[(size_t)s0 * 64 + lane];
                float f1 = Ap[(size_t)s1 * 64 + lane];
                float f2 = Ap[(size_t)s2 * 64 + lane];
                float f3 = Ap[(size_t)s3 * 64 + lane];
                acc += f0; acc += f1; acc += f2; acc += f3;
            }
            for (; j < n; ++j) {
                int s0 = __shfl(el, j);
                acc += Ap[(size_t)s0 * 64 + lane];
            }
        }
        float dv = dinv[v];
        float h = dv * (acc + Ap[(size_t)v * 64 + lane] * dv) + b1[lane];
        h = h > 0.f ? h : 0.f;
        float a2 = 0.f;
#pragma unroll 8
        for (int k = 0; k < 64; ++k) {
            float hk = __shfl(h, k);
            if (lane < 40) a2 += hk * Ws[k * 40 + lane];
        }
        if (lane < 40) A2p[(size_t)v * 40 + lane] = a2 * dv;
    }
}

// Wave per node: gather A2p rows, z = dinv*(sum + A2p[v]*dinv) + b2,
// out = log_softmax(softmax(z)) over 40 cols.
__global__ void layer_out_kernel(const float* __restrict__ A2p, const int* __restrict__ esrc,
                                 const int* __restrict__ rowptr, const float* __restrict__ dinv,
                                 const float* __restrict__ b2, float* __restrict__ out, int N) {
    int gtid = blockIdx.x * blockDim.x + threadIdx.x;
    int wave = gtid >> 6, lane = threadIdx.x & 63;
    int nw = (gridDim.x * blockDim.x) >> 6;
    for (int v = wave; v < N; v += nw) {
        int i0 = rowptr[v], i1 = rowptr[v + 1];
        bool act = lane < 40;
        float acc = 0.f;
        for (int base = i0; base < i1; base += 64) {
            int n = min(64, i1 - base);
            int el = (lane < n) ? esrc[base + lane] : 0;
            int j = 0;
            for (; j + 4 <= n; j += 4) {
                int s0 = __shfl(el, j), s1 = __shfl(el, j + 1);
                int s2 = __shfl(el, j + 2), s3 = __shfl(el, j + 3);
                if (act) {
                    float f0 = A2p[(size_t)s0 * 40 + lane];
                    float f1 = A2p[(size_t)s1 * 40 + lane];
                    float f2 = A2p[(size_t)s2 * 40 + lane];
                    float f3 = A2p[(size_t)s3 * 40 + lane];
                    acc += f0; acc += f1; acc += f2; acc += f3;
                }
            }
            for (; j < n; ++j) {
                int s0 = __shfl(el, j);
                if (act) acc += A2p[(size_t)s0 * 40 + lane];
            }
        }
        float dv = dinv[v];
        float z = act ? dv * (acc + A2p[(size_t)v * 40 + lane] * dv) + b2[lane] : -INFINITY;
        float m = z;
        for (int off = 32; off; off >>= 1) m = fmaxf(m, __shfl_xor(m, off));
        float e = act ? expf(z - m) : 0.f;
        float s = e;
        for (int off = 32; off; off >>= 1) s += __shfl_xor(s, off);
        float p = e / s;
        float m2 = act ? p : -INFINITY;
        for (int off = 32; off; off >>= 1) m2 = fmaxf(m2, __shfl_xor(m2, off));
        float e2 = act ? expf(p - m2) : 0.f;
        float s2 = e2;
        for (int off = 32; off; off >>= 1) s2 += __shfl_xor(s2, off);
        if (act) out[(size_t)v * 40 + lane] = (p - m2) - logf(s2);
    }
}

// ---------------- launch ----------------

extern "C" void kernel_launch(void* const* d_in, const int* in_sizes, int n_in,
                              void* d_out, int out_size, void* d_ws, size_t ws_size,
                              hipStream_t stream) {
    const float* x  = (const float*)d_in[0];
    const int*   ei = (const int*)d_in[1];
    const float* W1 = (const float*)d_in[2];
    const float* b1 = (const float*)d_in[3];
    const float* W2 = (const float*)d_in[4];
    const float* b2 = (const float*)d_in[5];
    float* out = (float*)d_out;

    int N = in_sizes[0] / 128;
    int E = in_sizes[1] / 2;
    const int* src = ei;
    const int* dst = ei + E;

    int nb = (N + 1023) / 1024;       // scan blocks (<= 256 required; 98 here)

    char* ws = (char*)d_ws;
    size_t o = 0;
    auto alloc = [&](size_t bytes) { void* p = ws + o; o += (bytes + 255) & ~(size_t)255; return p; };
    int*   cnt    = (int*)alloc((size_t)N * 4);
    int*   cursor = (int*)alloc((size_t)N * 4);
    float* dinv   = (float*)alloc((size_t)N * 4);
    int*   excl   = (int*)alloc((size_t)N * 4);
    int*   rowptr = (int*)alloc(((size_t)N + 1) * 4);
    int*   bsum   = (int*)alloc(1024);
    int*   bsum2  = (int*)alloc(1024);
    int*   esrc   = (int*)alloc((size_t)E * 4);
    float* Ap     = (float*)alloc((size_t)N * 64 * 4);
    float* A2p    = (float*)alloc((size_t)N * 40 * 4);

    // CSR build + degree norm
    hipMemsetAsync(cnt, 0, (size_t)N * 4, stream);
    deg_kernel<<<1024, 256, 0, stream>>>(dst, cnt, E);
    dinv_kernel<<<(N + 255) / 256, 256, 0, stream>>>(cnt, dinv, N);
    scan1_kernel<<<nb, 256, 0, stream>>>(cnt, excl, bsum, N);
    scan2_kernel<<<1, 256, 0, stream>>>(bsum, bsum2, nb);
    scan3_kernel<<<(N + 255) / 256, 256, 0, stream>>>(excl, bsum2, rowptr, cursor, N, E);
    bucket_kernel<<<2048, 256, 0, stream>>>(src, dst, cursor, esrc, E);

    // layer 1 linear (scaled): Ap = (x @ W1) * dinv
    gemm1_kernel<128, 64><<<1024, 256, 0, stream>>>(x, W1, dinv, Ap, N);
    // gather + relu + fused GEMM2 (scaled): A2p = (relu(...) @ W2) * dinv
    layer_mid_kernel<<<2048, 256, 0, stream>>>(Ap, esrc, rowptr, dinv, W2, b1, A2p, N);
    // gather + bias + softmax + log_softmax
    layer_out_kernel<<<2048, 256, 0, stream>>>(A2p, esrc, rowptr, dinv, b2, out, N);
}